// Round 1
// baseline (554.188 us; speedup 1.0000x reference)
//
#include <hip/hip_runtime.h>
#include <stdint.h>

#define N_NODES 50000
#define N_EDGES 800000
#define D 512
#define M_PAD 50048   // 391 * 128

typedef __attribute__((ext_vector_type(8))) __bf16 bf16x8;
typedef __attribute__((ext_vector_type(4))) float f32x4;

static __device__ __forceinline__ unsigned short f2bf(float f) {
  unsigned u = __float_as_uint(f);
  u += 0x7fff + ((u >> 16) & 1);   // round-to-nearest-even
  return (unsigned short)(u >> 16);
}
static __device__ __forceinline__ float bf2f(unsigned short h) {
  return __uint_as_float(((unsigned)h) << 16);
}

// ---- X (fp32, N_NODES x D) -> bf16, zero-padded to M_PAD rows ----
__global__ void k_cvt_x(const float* __restrict__ x, unsigned short* __restrict__ xb) {
  long long base = ((long long)blockIdx.x * blockDim.x + threadIdx.x) * 4;
  if (base >= (long long)M_PAD * D) return;
  int row = (int)(base >> 9);  // D = 512
  ushort4 o;
  if (row < N_NODES) {
    float4 v = *(const float4*)(x + base);
    o.x = f2bf(v.x); o.y = f2bf(v.y); o.z = f2bf(v.z); o.w = f2bf(v.w);
  } else {
    o.x = 0; o.y = 0; o.z = 0; o.w = 0;
  }
  *(ushort4*)(xb + base) = o;
}

// ---- W (fp32, K x N row-major) -> Wt bf16 (N x K) so B-fragments are contiguous in K ----
__global__ void k_cvt_wt(const float* __restrict__ w, unsigned short* __restrict__ wt) {
  int k = blockIdx.x;     // 512 blocks
  int n = threadIdx.x;    // 512 threads
  wt[n * D + k] = f2bf(w[k * D + n]);   // coalesced read, strided 2B write (0.5 MB total)
}

// ---- bf16 GEMM: C[M_PAD x D] = A[M_PAD x D] * Bt^T, 128x128 tile, 4 waves of 64x64 ----
__global__ __launch_bounds__(256) void k_gemm(const unsigned short* __restrict__ A,
                                              const unsigned short* __restrict__ Bt,
                                              unsigned short* __restrict__ C) {
  __shared__ unsigned short lds_a[128 * 32];
  __shared__ unsigned short lds_b[128 * 32];
  const int tid  = threadIdx.x;
  const int bm   = blockIdx.x >> 2;   // 391
  const int bn   = blockIdx.x & 3;    // 4
  const int m0   = bm * 128, n0 = bn * 128;
  const int wave = tid >> 6, lane = tid & 63;
  const int wm   = wave & 1, wn = wave >> 1;
  const int l15  = lane & 15, quad = lane >> 4;

  f32x4 acc[4][4];
#pragma unroll
  for (int i = 0; i < 4; i++)
#pragma unroll
    for (int j = 0; j < 4; j++) acc[i][j] = f32x4{0.f, 0.f, 0.f, 0.f};

  for (int kt = 0; kt < D / 32; ++kt) {
    const int k0 = kt * 32;
    __syncthreads();
#pragma unroll
    for (int c = 0; c < 2; c++) {
      int i = tid + c * 256;              // 16B chunk id, 0..511
      int r = i >> 2, kc = (i & 3) << 3;  // row in tile, k-elem offset
      *(uint4*)&lds_a[i << 3] = *(const uint4*)&A[(long long)(m0 + r) * D + k0 + kc];
      *(uint4*)&lds_b[i << 3] = *(const uint4*)&Bt[(n0 + r) * D + k0 + kc];
    }
    __syncthreads();
    bf16x8 af[4], bfr[4];
#pragma unroll
    for (int t = 0; t < 4; t++) {
      af[t]  = *(const bf16x8*)&lds_a[(wm * 64 + t * 16 + l15) * 32 + quad * 8];
      bfr[t] = *(const bf16x8*)&lds_b[(wn * 64 + t * 16 + l15) * 32 + quad * 8];
    }
#pragma unroll
    for (int i = 0; i < 4; i++)
#pragma unroll
      for (int j = 0; j < 4; j++)
        acc[i][j] = __builtin_amdgcn_mfma_f32_16x16x32_bf16(af[i], bfr[j], acc[i][j], 0, 0, 0);
  }
  // epilogue: C/D layout col=lane&15, row=quad*4+reg  [m89/m91 verified]
#pragma unroll
  for (int i = 0; i < 4; i++)
#pragma unroll
    for (int j = 0; j < 4; j++)
#pragma unroll
      for (int r = 0; r < 4; r++) {
        int row = m0 + wm * 64 + i * 16 + quad * 4 + r;
        int col = n0 + wn * 64 + j * 16 + l15;
        C[(long long)row * D + col] = f2bf(acc[i][j][r]);
      }
}

// ---- CSR-by-destination build ----
__global__ void k_zero(int* deg) {
  int i = blockIdx.x * 256 + threadIdx.x;
  if (i < N_NODES) deg[i] = 0;
}
__global__ void k_hist(const int* __restrict__ dst, int* deg) {
  int e = blockIdx.x * 256 + threadIdx.x;
  if (e < N_EDGES) atomicAdd(&deg[dst[e]], 1);
}
__global__ void k_scan(const int* __restrict__ deg, int* __restrict__ off, int* __restrict__ cur) {
  __shared__ int sums[256];
  const int CH = 196;                 // 196*256 = 50176 >= N_NODES
  int t  = threadIdx.x;
  int lo = t * CH, hi = min(lo + CH, N_NODES);
  int s = 0;
  for (int i = lo; i < hi; i++) s += deg[i];
  sums[t] = s;
  __syncthreads();
  if (t == 0) {
    int run = 0;
    for (int i = 0; i < 256; i++) { int v = sums[i]; sums[i] = run; run += v; }
  }
  __syncthreads();
  int run = sums[t];
  for (int i = lo; i < hi; i++) { off[i] = run; cur[i] = run; run += deg[i]; }
  if (t == 255) off[N_NODES] = run;
}
__global__ void k_fill(const int* __restrict__ src, const int* __restrict__ dst,
                       const float* __restrict__ w, int* cur,
                       int* __restrict__ csrc, float* __restrict__ cw) {
  int e = blockIdx.x * 256 + threadIdx.x;
  if (e >= N_EDGES) return;
  int d = dst[e];
  int p = atomicAdd(&cur[d], 1);
  csrc[p] = src[e];
  cw[p]   = w[e];
}

// ---- aggregate: one block per dst node, no output atomics ----
__global__ __launch_bounds__(256) void k_agg(const int* __restrict__ off, const int* __restrict__ csrc,
                                             const float* __restrict__ cw,
                                             const unsigned short* __restrict__ S,
                                             float* __restrict__ out) {
  __shared__ int   s_src[256];
  __shared__ float s_w[256];
  int node  = blockIdx.x;
  int start = off[node], end = off[node + 1];
  int col   = threadIdx.x * 2;
  float a0 = 0.f, a1 = 0.f;
  for (int cs = start; cs < end; cs += 256) {
    int n = min(256, end - cs);
    if ((int)threadIdx.x < n) {
      s_src[threadIdx.x] = csrc[cs + threadIdx.x];
      s_w[threadIdx.x]   = cw[cs + threadIdx.x];
    }
    __syncthreads();
    for (int i = 0; i < n; i++) {
      unsigned v = *(const unsigned*)(S + (long long)s_src[i] * D + col);  // 4B/lane, coalesced
      float w = s_w[i];
      a0 = fmaf(w, bf2f((unsigned short)(v & 0xffffu)), a0);
      a1 = fmaf(w, bf2f((unsigned short)(v >> 16)), a1);
    }
    __syncthreads();
  }
  *(float2*)(out + (long long)node * D + col) = make_float2(a0, a1);
}

extern "C" void kernel_launch(void* const* d_in, const int* in_sizes, int n_in,
                              void* d_out, int out_size, void* d_ws, size_t ws_size,
                              hipStream_t stream) {
  const float* x    = (const float*)d_in[0];
  const float* w    = (const float*)d_in[1];
  const float* ew   = (const float*)d_in[2];
  const int*   esrc = (const int*)d_in[3];
  const int*   edst = (const int*)d_in[4];
  float* out = (float*)d_out;

  // workspace layout (256B aligned slabs), ~110 MB total
  char* p = (char*)d_ws;
  auto align256 = [](size_t v) { return (v + 255) & ~(size_t)255; };
  unsigned short* xb = (unsigned short*)p;  p += align256((size_t)M_PAD * D * 2);
  unsigned short* sb = (unsigned short*)p;  p += align256((size_t)M_PAD * D * 2);
  unsigned short* wt = (unsigned short*)p;  p += align256((size_t)D * D * 2);
  int*   deg  = (int*)p;   p += align256((size_t)N_NODES * 4);
  int*   off  = (int*)p;   p += align256((size_t)(N_NODES + 1) * 4);
  int*   cur  = (int*)p;   p += align256((size_t)N_NODES * 4);
  int*   csrc = (int*)p;   p += align256((size_t)N_EDGES * 4);
  float* cw   = (float*)p; p += align256((size_t)N_EDGES * 4);

  // stage 0: casts
  k_cvt_x<<<(M_PAD * D / 4 + 255) / 256, 256, 0, stream>>>(x, xb);
  k_cvt_wt<<<D, D, 0, stream>>>(w, wt);
  // stage 1: support = X @ W  (bf16 MFMA, output bf16)
  k_gemm<<<391 * 4, 256, 0, stream>>>(xb, wt, sb);
  // stage 2a: CSR build by destination
  k_zero<<<(N_NODES + 255) / 256, 256, 0, stream>>>(deg);
  k_hist<<<(N_EDGES + 255) / 256, 256, 0, stream>>>(edst, deg);
  k_scan<<<1, 256, 0, stream>>>(deg, off, cur);
  k_fill<<<(N_EDGES + 255) / 256, 256, 0, stream>>>(esrc, edst, ew, cur, csrc, cw);
  // stage 2b: aggregate, one block per node
  k_agg<<<N_NODES, 256, 0, stream>>>(off, csrc, cw, sb, out);
}

// Round 2
// 440.249 us; speedup vs baseline: 1.2588x; 1.2588x over previous
//
#include <hip/hip_runtime.h>
#include <stdint.h>

#define N_NODES 50000
#define N_EDGES 800000
#define D 512
#define M_PAD 50048    // 391 * 128
#define SCAN_NB 196    // 196*256 = 50176 >= N_NODES

typedef __attribute__((ext_vector_type(8))) __bf16 bf16x8;
typedef __attribute__((ext_vector_type(4))) float f32x4;

static __device__ __forceinline__ unsigned short f2bf(float f) {
  unsigned u = __float_as_uint(f);
  u += 0x7fff + ((u >> 16) & 1);   // round-to-nearest-even
  return (unsigned short)(u >> 16);
}
static __device__ __forceinline__ float bf2f(unsigned short h) {
  return __uint_as_float(((unsigned)h) << 16);
}

// ---- X (fp32, N_NODES x D) -> bf16, zero-padded to M_PAD rows ----
__global__ void k_cvt_x(const float* __restrict__ x, unsigned short* __restrict__ xb) {
  long long base = ((long long)blockIdx.x * blockDim.x + threadIdx.x) * 4;
  if (base >= (long long)M_PAD * D) return;
  int row = (int)(base >> 9);  // D = 512
  ushort4 o;
  if (row < N_NODES) {
    float4 v = *(const float4*)(x + base);
    o.x = f2bf(v.x); o.y = f2bf(v.y); o.z = f2bf(v.z); o.w = f2bf(v.w);
  } else {
    o.x = 0; o.y = 0; o.z = 0; o.w = 0;
  }
  *(ushort4*)(xb + base) = o;
}

// ---- W (fp32, K x N row-major) -> Wt bf16 (N x K) ----
__global__ void k_cvt_wt(const float* __restrict__ w, unsigned short* __restrict__ wt) {
  int k = blockIdx.x;     // 512 blocks
  int n = threadIdx.x;    // 512 threads
  wt[n * D + k] = f2bf(w[k * D + n]);
}

// ---- bf16 GEMM: C[M_PAD x D] = A * Bt^T, 128x128 tile, 4 waves of 64x64 ----
__global__ __launch_bounds__(256) void k_gemm(const unsigned short* __restrict__ A,
                                              const unsigned short* __restrict__ Bt,
                                              unsigned short* __restrict__ C) {
  __shared__ unsigned short lds_a[128 * 32];
  __shared__ unsigned short lds_b[128 * 32];
  const int tid  = threadIdx.x;
  const int bm   = blockIdx.x >> 2;   // 391
  const int bn   = blockIdx.x & 3;    // 4
  const int m0   = bm * 128, n0 = bn * 128;
  const int wave = tid >> 6, lane = tid & 63;
  const int wm   = wave & 1, wn = wave >> 1;
  const int l15  = lane & 15, quad = lane >> 4;

  f32x4 acc[4][4];
#pragma unroll
  for (int i = 0; i < 4; i++)
#pragma unroll
    for (int j = 0; j < 4; j++) acc[i][j] = f32x4{0.f, 0.f, 0.f, 0.f};

  for (int kt = 0; kt < D / 32; ++kt) {
    const int k0 = kt * 32;
    __syncthreads();
#pragma unroll
    for (int c = 0; c < 2; c++) {
      int i = tid + c * 256;
      int r = i >> 2, kc = (i & 3) << 3;
      *(uint4*)&lds_a[i << 3] = *(const uint4*)&A[(long long)(m0 + r) * D + k0 + kc];
      *(uint4*)&lds_b[i << 3] = *(const uint4*)&Bt[(n0 + r) * D + k0 + kc];
    }
    __syncthreads();
    bf16x8 af[4], bfr[4];
#pragma unroll
    for (int t = 0; t < 4; t++) {
      af[t]  = *(const bf16x8*)&lds_a[(wm * 64 + t * 16 + l15) * 32 + quad * 8];
      bfr[t] = *(const bf16x8*)&lds_b[(wn * 64 + t * 16 + l15) * 32 + quad * 8];
    }
#pragma unroll
    for (int i = 0; i < 4; i++)
#pragma unroll
      for (int j = 0; j < 4; j++)
        acc[i][j] = __builtin_amdgcn_mfma_f32_16x16x32_bf16(af[i], bfr[j], acc[i][j], 0, 0, 0);
  }
#pragma unroll
  for (int i = 0; i < 4; i++)
#pragma unroll
    for (int j = 0; j < 4; j++)
#pragma unroll
      for (int r = 0; r < 4; r++) {
        int row = m0 + wm * 64 + i * 16 + quad * 4 + r;
        int col = n0 + wn * 64 + j * 16 + l15;
        C[(long long)row * D + col] = f2bf(acc[i][j][r]);
      }
}

// ---- CSR-by-destination build ----
__global__ void k_zero(int* deg) {
  int i = blockIdx.x * 256 + threadIdx.x;
  if (i < N_NODES) deg[i] = 0;
}
__global__ void k_hist(const int* __restrict__ dst, int* deg) {
  int e = blockIdx.x * 256 + threadIdx.x;
  if (e < N_EDGES) atomicAdd(&deg[dst[e]], 1);
}

// ---- parallel 3-pass exclusive scan (replaces 121 µs single-block scan) ----
__global__ void k_scan1(const int* __restrict__ deg, int* __restrict__ bsum) {
  __shared__ int red[256];
  int i = blockIdx.x * 256 + threadIdx.x;
  red[threadIdx.x] = (i < N_NODES) ? deg[i] : 0;
  __syncthreads();
#pragma unroll
  for (int s = 128; s > 0; s >>= 1) {
    if ((int)threadIdx.x < s) red[threadIdx.x] += red[threadIdx.x + s];
    __syncthreads();
  }
  if (threadIdx.x == 0) bsum[blockIdx.x] = red[0];
}
__global__ void k_scan2(int* __restrict__ bsum) {   // 1 block, 256 threads
  __shared__ int tmp[256];
  int t = threadIdx.x;
  int v = (t < SCAN_NB) ? bsum[t] : 0;
  tmp[t] = v;
  __syncthreads();
#pragma unroll
  for (int s = 1; s < 256; s <<= 1) {
    int add = (t >= s) ? tmp[t - s] : 0;
    __syncthreads();
    tmp[t] += add;
    __syncthreads();
  }
  if (t < SCAN_NB) bsum[t] = tmp[t] - v;   // exclusive
}
__global__ void k_scan3(const int* __restrict__ deg, const int* __restrict__ bsum,
                        int* __restrict__ off, int* __restrict__ cur) {
  __shared__ int tmp[256];
  int t = threadIdx.x, i = blockIdx.x * 256 + t;
  int v = (i < N_NODES) ? deg[i] : 0;
  tmp[t] = v;
  __syncthreads();
#pragma unroll
  for (int s = 1; s < 256; s <<= 1) {
    int add = (t >= s) ? tmp[t - s] : 0;
    __syncthreads();
    tmp[t] += add;
    __syncthreads();
  }
  int pre = tmp[t] - v + bsum[blockIdx.x];
  if (i < N_NODES) {
    off[i] = pre;
    cur[i] = pre;
    if (i == N_NODES - 1) off[N_NODES] = pre + v;
  }
}

__global__ void k_fill(const int* __restrict__ src, const int* __restrict__ dst,
                       const float* __restrict__ w, int* cur,
                       int* __restrict__ csrc, float* __restrict__ cw) {
  int e = blockIdx.x * 256 + threadIdx.x;
  if (e >= N_EDGES) return;
  int d = dst[e];
  int p = atomicAdd(&cur[d], 1);
  csrc[p] = src[e];
  cw[p]   = w[e];
}

// ---- aggregate: one block per dst node; 4-wide edge unroll for MLP ----
__global__ __launch_bounds__(256) void k_agg(const int* __restrict__ off, const int* __restrict__ csrc,
                                             const float* __restrict__ cw,
                                             const unsigned short* __restrict__ S,
                                             float* __restrict__ out) {
  __shared__ int   s_src[256];
  __shared__ float s_w[256];
  int node  = blockIdx.x;
  int start = off[node], end = off[node + 1];
  int col   = threadIdx.x * 2;
  float a0 = 0.f, a1 = 0.f;
  for (int cs = start; cs < end; cs += 256) {
    int n = min(256, end - cs);
    if ((int)threadIdx.x < n) {
      s_src[threadIdx.x] = csrc[cs + threadIdx.x];
      s_w[threadIdx.x]   = cw[cs + threadIdx.x];
    }
    __syncthreads();
    int i = 0;
    for (; i + 4 <= n; i += 4) {
      unsigned v0 = *(const unsigned*)(S + (long long)s_src[i + 0] * D + col);
      unsigned v1 = *(const unsigned*)(S + (long long)s_src[i + 1] * D + col);
      unsigned v2 = *(const unsigned*)(S + (long long)s_src[i + 2] * D + col);
      unsigned v3 = *(const unsigned*)(S + (long long)s_src[i + 3] * D + col);
      float w0 = s_w[i], w1 = s_w[i + 1], w2 = s_w[i + 2], w3 = s_w[i + 3];
      a0 = fmaf(w0, bf2f((unsigned short)(v0 & 0xffffu)), a0);
      a1 = fmaf(w0, bf2f((unsigned short)(v0 >> 16)), a1);
      a0 = fmaf(w1, bf2f((unsigned short)(v1 & 0xffffu)), a0);
      a1 = fmaf(w1, bf2f((unsigned short)(v1 >> 16)), a1);
      a0 = fmaf(w2, bf2f((unsigned short)(v2 & 0xffffu)), a0);
      a1 = fmaf(w2, bf2f((unsigned short)(v2 >> 16)), a1);
      a0 = fmaf(w3, bf2f((unsigned short)(v3 & 0xffffu)), a0);
      a1 = fmaf(w3, bf2f((unsigned short)(v3 >> 16)), a1);
    }
    for (; i < n; i++) {
      unsigned v = *(const unsigned*)(S + (long long)s_src[i] * D + col);
      float w = s_w[i];
      a0 = fmaf(w, bf2f((unsigned short)(v & 0xffffu)), a0);
      a1 = fmaf(w, bf2f((unsigned short)(v >> 16)), a1);
    }
    __syncthreads();
  }
  *(float2*)(out + (long long)node * D + col) = make_float2(a0, a1);
}

extern "C" void kernel_launch(void* const* d_in, const int* in_sizes, int n_in,
                              void* d_out, int out_size, void* d_ws, size_t ws_size,
                              hipStream_t stream) {
  const float* x    = (const float*)d_in[0];
  const float* w    = (const float*)d_in[1];
  const float* ew   = (const float*)d_in[2];
  const int*   esrc = (const int*)d_in[3];
  const int*   edst = (const int*)d_in[4];
  float* out = (float*)d_out;

  char* p = (char*)d_ws;
  auto align256 = [](size_t v) { return (v + 255) & ~(size_t)255; };
  unsigned short* xb = (unsigned short*)p;  p += align256((size_t)M_PAD * D * 2);
  unsigned short* sb = (unsigned short*)p;  p += align256((size_t)M_PAD * D * 2);
  unsigned short* wt = (unsigned short*)p;  p += align256((size_t)D * D * 2);
  int*   deg  = (int*)p;   p += align256((size_t)N_NODES * 4);
  int*   off  = (int*)p;   p += align256((size_t)(N_NODES + 1) * 4);
  int*   cur  = (int*)p;   p += align256((size_t)N_NODES * 4);
  int*   csrc = (int*)p;   p += align256((size_t)N_EDGES * 4);
  float* cw   = (float*)p; p += align256((size_t)N_EDGES * 4);
  int*   bsum = (int*)p;   p += align256((size_t)256 * 4);

  // stage 0: casts
  k_cvt_x<<<(M_PAD * D / 4 + 255) / 256, 256, 0, stream>>>(x, xb);
  k_cvt_wt<<<D, D, 0, stream>>>(w, wt);
  // stage 1: support = X @ W  (bf16 MFMA, output bf16)
  k_gemm<<<391 * 4, 256, 0, stream>>>(xb, wt, sb);
  // stage 2a: CSR build by destination (parallel scan)
  k_zero<<<(N_NODES + 255) / 256, 256, 0, stream>>>(deg);
  k_hist<<<(N_EDGES + 255) / 256, 256, 0, stream>>>(edst, deg);
  k_scan1<<<SCAN_NB, 256, 0, stream>>>(deg, bsum);
  k_scan2<<<1, 256, 0, stream>>>(bsum);
  k_scan3<<<SCAN_NB, 256, 0, stream>>>(deg, bsum, off, cur);
  k_fill<<<(N_EDGES + 255) / 256, 256, 0, stream>>>(esrc, edst, ew, cur, csrc, cw);
  // stage 2b: aggregate, one block per node
  k_agg<<<N_NODES, 256, 0, stream>>>(off, csrc, cw, sb, out);
}

// Round 3
// 437.198 us; speedup vs baseline: 1.2676x; 1.0070x over previous
//
#include <hip/hip_runtime.h>
#include <stdint.h>

#define N_NODES 50000
#define N_EDGES 800000
#define D 512
#define M_PAD 50048    // 391 * 128
#define SCAN_NB 196    // 196*256 = 50176 >= N_NODES

typedef __attribute__((ext_vector_type(8))) __bf16 bf16x8;
typedef __attribute__((ext_vector_type(4))) float f32x4;

static __device__ __forceinline__ unsigned short f2bf(float f) {
  unsigned u = __float_as_uint(f);
  u += 0x7fff + ((u >> 16) & 1);   // round-to-nearest-even
  return (unsigned short)(u >> 16);
}
static __device__ __forceinline__ float bf2f(unsigned short h) {
  return __uint_as_float(((unsigned)h) << 16);
}

// async global->LDS, 16B per lane; LDS base must be wave-uniform (lane-linear fill)
static __device__ __forceinline__ void gload_lds16(const void* g, void* l) {
  __builtin_amdgcn_global_load_lds((const __attribute__((address_space(1))) unsigned*)g,
                                   (__attribute__((address_space(3))) unsigned*)l, 16, 0, 0);
}

// ---- X (fp32, N_NODES x D) -> bf16, zero-padded to M_PAD rows ----
__global__ void k_cvt_x(const float* __restrict__ x, unsigned short* __restrict__ xb) {
  long long base = ((long long)blockIdx.x * blockDim.x + threadIdx.x) * 4;
  if (base >= (long long)M_PAD * D) return;
  int row = (int)(base >> 9);  // D = 512
  ushort4 o;
  if (row < N_NODES) {
    float4 v = *(const float4*)(x + base);
    o.x = f2bf(v.x); o.y = f2bf(v.y); o.z = f2bf(v.z); o.w = f2bf(v.w);
  } else {
    o.x = 0; o.y = 0; o.z = 0; o.w = 0;
  }
  *(ushort4*)(xb + base) = o;
}

// ---- W (fp32, K x N row-major) -> Wt bf16 (N x K) ----
__global__ void k_cvt_wt(const float* __restrict__ w, unsigned short* __restrict__ wt) {
  int k = blockIdx.x;     // 512 blocks
  int n = threadIdx.x;    // 512 threads
  wt[n * D + k] = f2bf(w[k * D + n]);
}

// ---- bf16 GEMM: C[M_PAD x D] = A * Bt^T, 128x128 tile, global_load_lds staging ----
__global__ __launch_bounds__(256) void k_gemm(const unsigned short* __restrict__ A,
                                              const unsigned short* __restrict__ Bt,
                                              unsigned short* __restrict__ C) {
  __shared__ unsigned short lds_a[128 * 32];
  __shared__ unsigned short lds_b[128 * 32];
  const int tid  = threadIdx.x;
  const int bm   = blockIdx.x >> 2;   // 391
  const int bn   = blockIdx.x & 3;    // 4
  const int m0   = bm * 128, n0 = bn * 128;
  const int wave = tid >> 6, lane = tid & 63;
  const int wm   = wave & 1, wn = wave >> 1;
  const int l15  = lane & 15, quad = lane >> 4;

  f32x4 acc[4][4];
#pragma unroll
  for (int i = 0; i < 4; i++)
#pragma unroll
    for (int j = 0; j < 4; j++) acc[i][j] = f32x4{0.f, 0.f, 0.f, 0.f};

  for (int kt = 0; kt < D / 32; ++kt) {
    const int k0 = kt * 32;
    __syncthreads();
#pragma unroll
    for (int c = 0; c < 2; c++) {
      int i = c * 256 + wave * 64 + lane;   // 16B chunk id, lane-linear per wave
      int r = i >> 2, kc = (i & 3) << 3;
      gload_lds16(&A[(long long)(m0 + r) * D + k0 + kc], &lds_a[(c * 256 + wave * 64) * 8]);
      gload_lds16(&Bt[(long long)(n0 + r) * D + k0 + kc], &lds_b[(c * 256 + wave * 64) * 8]);
    }
    __syncthreads();
    bf16x8 af[4], bfr[4];
#pragma unroll
    for (int t = 0; t < 4; t++) {
      af[t]  = *(const bf16x8*)&lds_a[(wm * 64 + t * 16 + l15) * 32 + quad * 8];
      bfr[t] = *(const bf16x8*)&lds_b[(wn * 64 + t * 16 + l15) * 32 + quad * 8];
    }
#pragma unroll
    for (int i = 0; i < 4; i++)
#pragma unroll
      for (int j = 0; j < 4; j++)
        acc[i][j] = __builtin_amdgcn_mfma_f32_16x16x32_bf16(af[i], bfr[j], acc[i][j], 0, 0, 0);
  }
#pragma unroll
  for (int i = 0; i < 4; i++)
#pragma unroll
    for (int j = 0; j < 4; j++)
#pragma unroll
      for (int r = 0; r < 4; r++) {
        int row = m0 + wm * 64 + i * 16 + quad * 4 + r;
        int col = n0 + wn * 64 + j * 16 + l15;
        C[(long long)row * D + col] = f2bf(acc[i][j][r]);
      }
}

// ---- CSR-by-destination build ----
__global__ void k_zero(int* deg) {
  int i = blockIdx.x * 256 + threadIdx.x;
  if (i < N_NODES) deg[i] = 0;
}
__global__ void k_hist(const int* __restrict__ dst, int* deg) {
  int e = blockIdx.x * 256 + threadIdx.x;
  if (e < N_EDGES) atomicAdd(&deg[dst[e]], 1);
}

__global__ void k_scan1(const int* __restrict__ deg, int* __restrict__ bsum) {
  __shared__ int red[256];
  int i = blockIdx.x * 256 + threadIdx.x;
  red[threadIdx.x] = (i < N_NODES) ? deg[i] : 0;
  __syncthreads();
#pragma unroll
  for (int s = 128; s > 0; s >>= 1) {
    if ((int)threadIdx.x < s) red[threadIdx.x] += red[threadIdx.x + s];
    __syncthreads();
  }
  if (threadIdx.x == 0) bsum[blockIdx.x] = red[0];
}
__global__ void k_scan2(int* __restrict__ bsum) {   // 1 block, 256 threads
  __shared__ int tmp[256];
  int t = threadIdx.x;
  int v = (t < SCAN_NB) ? bsum[t] : 0;
  tmp[t] = v;
  __syncthreads();
#pragma unroll
  for (int s = 1; s < 256; s <<= 1) {
    int add = (t >= s) ? tmp[t - s] : 0;
    __syncthreads();
    tmp[t] += add;
    __syncthreads();
  }
  if (t < SCAN_NB) bsum[t] = tmp[t] - v;   // exclusive
}
__global__ void k_scan3(const int* __restrict__ deg, const int* __restrict__ bsum,
                        int* __restrict__ off, int* __restrict__ cur) {
  __shared__ int tmp[256];
  int t = threadIdx.x, i = blockIdx.x * 256 + t;
  int v = (i < N_NODES) ? deg[i] : 0;
  tmp[t] = v;
  __syncthreads();
#pragma unroll
  for (int s = 1; s < 256; s <<= 1) {
    int add = (t >= s) ? tmp[t - s] : 0;
    __syncthreads();
    tmp[t] += add;
    __syncthreads();
  }
  int pre = tmp[t] - v + bsum[blockIdx.x];
  if (i < N_NODES) {
    off[i] = pre;
    cur[i] = pre;
    if (i == N_NODES - 1) off[N_NODES] = pre + v;
  }
}

__global__ void k_fill(const int* __restrict__ src, const int* __restrict__ dst,
                       const float* __restrict__ w, int* cur,
                       int* __restrict__ csrc, float* __restrict__ cw) {
  int e = blockIdx.x * 256 + threadIdx.x;
  if (e >= N_EDGES) return;
  int d = dst[e];
  int p = atomicAdd(&cur[d], 1);
  csrc[p] = src[e];
  cw[p]   = w[e];
}

// ---- aggregate: one wave = one full edge-row via dwordx4 (1 VMEM instr / KB) ----
__global__ __launch_bounds__(256) void k_agg(const int* __restrict__ off, const int* __restrict__ csrc,
                                             const float* __restrict__ cw,
                                             const unsigned short* __restrict__ S,
                                             float* __restrict__ out) {
  __shared__ float s_part[4 * 512];
  const int node  = blockIdx.x;
  const int start = off[node], end = off[node + 1];
  const int wave  = threadIdx.x >> 6, lane = threadIdx.x & 63;
  float a[8];
#pragma unroll
  for (int k = 0; k < 8; k++) a[k] = 0.f;

#define EDGE_FMA(V, W)                                             \
  do {                                                             \
    a[0] = fmaf(W, bf2f((unsigned short)(V.x & 0xffffu)), a[0]);   \
    a[1] = fmaf(W, bf2f((unsigned short)(V.x >> 16)),     a[1]);   \
    a[2] = fmaf(W, bf2f((unsigned short)(V.y & 0xffffu)), a[2]);   \
    a[3] = fmaf(W, bf2f((unsigned short)(V.y >> 16)),     a[3]);   \
    a[4] = fmaf(W, bf2f((unsigned short)(V.z & 0xffffu)), a[4]);   \
    a[5] = fmaf(W, bf2f((unsigned short)(V.z >> 16)),     a[5]);   \
    a[6] = fmaf(W, bf2f((unsigned short)(V.w & 0xffffu)), a[6]);   \
    a[7] = fmaf(W, bf2f((unsigned short)(V.w >> 16)),     a[7]);   \
  } while (0)

  int e = start + wave;
  // 2-deep pipelined pairs: issue both gathers before either FMA block
  for (; e + 4 < end; e += 8) {
    int   s0 = csrc[e],     s1 = csrc[e + 4];      // wave-uniform broadcast loads
    float w0 = cw[e],       w1 = cw[e + 4];
    uint4 v0 = *(const uint4*)(S + (size_t)s0 * D + lane * 8);
    uint4 v1 = *(const uint4*)(S + (size_t)s1 * D + lane * 8);
    EDGE_FMA(v0, w0);
    EDGE_FMA(v1, w1);
  }
  if (e < end) {
    int   s0 = csrc[e];
    float w0 = cw[e];
    uint4 v0 = *(const uint4*)(S + (size_t)s0 * D + lane * 8);
    EDGE_FMA(v0, w0);
  }
#undef EDGE_FMA

  // cross-wave combine
  float4* sp = (float4*)&s_part[wave * 512 + lane * 8];
  sp[0] = make_float4(a[0], a[1], a[2], a[3]);
  sp[1] = make_float4(a[4], a[5], a[6], a[7]);
  __syncthreads();
  int col = threadIdx.x * 2;
  float2 r0 = *(const float2*)&s_part[0 * 512 + col];
  float2 r1 = *(const float2*)&s_part[1 * 512 + col];
  float2 r2 = *(const float2*)&s_part[2 * 512 + col];
  float2 r3 = *(const float2*)&s_part[3 * 512 + col];
  *(float2*)(out + (size_t)node * D + col) =
      make_float2(r0.x + r1.x + r2.x + r3.x, r0.y + r1.y + r2.y + r3.y);
}

extern "C" void kernel_launch(void* const* d_in, const int* in_sizes, int n_in,
                              void* d_out, int out_size, void* d_ws, size_t ws_size,
                              hipStream_t stream) {
  const float* x    = (const float*)d_in[0];
  const float* w    = (const float*)d_in[1];
  const float* ew   = (const float*)d_in[2];
  const int*   esrc = (const int*)d_in[3];
  const int*   edst = (const int*)d_in[4];
  float* out = (float*)d_out;

  char* p = (char*)d_ws;
  auto align256 = [](size_t v) { return (v + 255) & ~(size_t)255; };
  unsigned short* xb = (unsigned short*)p;  p += align256((size_t)M_PAD * D * 2);
  unsigned short* sb = (unsigned short*)p;  p += align256((size_t)M_PAD * D * 2);
  unsigned short* wt = (unsigned short*)p;  p += align256((size_t)D * D * 2);
  int*   deg  = (int*)p;   p += align256((size_t)N_NODES * 4);
  int*   off  = (int*)p;   p += align256((size_t)(N_NODES + 1) * 4);
  int*   cur  = (int*)p;   p += align256((size_t)N_NODES * 4);
  int*   csrc = (int*)p;   p += align256((size_t)N_EDGES * 4);
  float* cw   = (float*)p; p += align256((size_t)N_EDGES * 4);
  int*   bsum = (int*)p;   p += align256((size_t)256 * 4);

  // stage 0: casts
  k_cvt_x<<<(M_PAD * D / 4 + 255) / 256, 256, 0, stream>>>(x, xb);
  k_cvt_wt<<<D, D, 0, stream>>>(w, wt);
  // stage 1: support = X @ W  (bf16 MFMA, output bf16)
  k_gemm<<<391 * 4, 256, 0, stream>>>(xb, wt, sb);
  // stage 2a: CSR build by destination (parallel scan)
  k_zero<<<(N_NODES + 255) / 256, 256, 0, stream>>>(deg);
  k_hist<<<(N_EDGES + 255) / 256, 256, 0, stream>>>(edst, deg);
  k_scan1<<<SCAN_NB, 256, 0, stream>>>(deg, bsum);
  k_scan2<<<1, 256, 0, stream>>>(bsum);
  k_scan3<<<SCAN_NB, 256, 0, stream>>>(deg, bsum, off, cur);
  k_fill<<<(N_EDGES + 255) / 256, 256, 0, stream>>>(esrc, edst, ew, cur, csrc, cw);
  // stage 2b: aggregate, one block per node
  k_agg<<<N_NODES, 256, 0, stream>>>(off, csrc, cw, sb, out);
}